// Round 1
// baseline (1036.530 us; speedup 1.0000x reference)
//
#include <hip/hip_runtime.h>
#include <math.h>

// ---------------------------------------------------------------------------
// MACE layer, f32 baseline.
// Pipeline:
//   0. memset agg[N][9][128] = 0
//   1. h = node_feats @ W_up                      (k_gemm128)
//   2. per-edge radial MLP + messages + atomic scatter into agg   (k_edge)
//   3. s,v,t = (agg/16) @ {Wl0,Wl1,Wl2}           (k_gemm128 x3, batched rows)
//   4. symmetric contraction -> B0,B1             (k_contract, elementwise)
//   5. h0 = B0@P0 ; h1 = B1@P1                    (k_gemm128 x2)
//   6. readout: z=silu(h0@W1+b1), scal=z@W2, gate=z@W3, vec; write outputs
// ---------------------------------------------------------------------------

__device__ __forceinline__ float rl_f(float v, int lane) {
  // broadcast lane's value to all lanes (uniform index -> v_readlane -> SGPR)
  return __uint_as_float(__builtin_amdgcn_readlane(__float_as_uint(v), lane));
}

// ---------------- generic 128->128 GEMM: out = (scale*in) @ W --------------
// row r addressing: ptr = base + (r/gs)*nstride + (r%gs)*cstride
__global__ __launch_bounds__(256) void k_gemm128(
    const float* __restrict__ in, const float* __restrict__ W,
    float* __restrict__ out, int M, int gs,
    int nstride, int cstride, int onstride, int ocstride, float scale)
{
  __shared__ float sW[128 * 128];
  {
    const float4* src = (const float4*)W;
    float4* dst = (float4*)sW;
    for (int i = threadIdx.x; i < 128 * 128 / 4; i += blockDim.x) dst[i] = src[i];
  }
  __syncthreads();
  const int l  = threadIdx.x & 63;
  const int gw = (int)((blockIdx.x * blockDim.x + threadIdx.x) >> 6);
  const int nw = (int)((gridDim.x * blockDim.x) >> 6);
  const int nch = (M + 7) >> 3;
  for (int ch = gw; ch < nch; ch += nw) {
    const int r0 = ch * 8;
    float a_lo[8], a_hi[8], acc_lo[8], acc_hi[8];
#pragma unroll
    for (int e = 0; e < 8; ++e) {
      int r = r0 + e; if (r >= M) r = M - 1;
      const float* rp = in + (size_t)(r / gs) * nstride + (size_t)(r % gs) * cstride;
      a_lo[e] = rp[l] * scale;
      a_hi[e] = rp[64 + l] * scale;
      acc_lo[e] = 0.f; acc_hi[e] = 0.f;
    }
    for (int c = 0; c < 64; ++c) {
      const float w_lo = sW[c * 128 + l];
      const float w_hi = sW[c * 128 + 64 + l];
#pragma unroll
      for (int e = 0; e < 8; ++e) {
        const float a = rl_f(a_lo[e], c);
        acc_lo[e] = fmaf(a, w_lo, acc_lo[e]);
        acc_hi[e] = fmaf(a, w_hi, acc_hi[e]);
      }
    }
    for (int c = 0; c < 64; ++c) {
      const float w_lo = sW[(64 + c) * 128 + l];
      const float w_hi = sW[(64 + c) * 128 + 64 + l];
#pragma unroll
      for (int e = 0; e < 8; ++e) {
        const float a = rl_f(a_hi[e], c);
        acc_lo[e] = fmaf(a, w_lo, acc_lo[e]);
        acc_hi[e] = fmaf(a, w_hi, acc_hi[e]);
      }
    }
#pragma unroll
    for (int e = 0; e < 8; ++e) {
      const int r = r0 + e; if (r >= M) break;
      float* op = out + (size_t)(r / gs) * onstride + (size_t)(r % gs) * ocstride;
      op[l] = acc_lo[e];
      op[64 + l] = acc_hi[e];
    }
  }
}

// ---------------- edge kernel: radial MLP + messages + atomic scatter ------
__global__ __launch_bounds__(256) void k_edge(
    const float* __restrict__ vectors, const float* __restrict__ lengths,
    const float* __restrict__ edge_feats, const int* __restrict__ eidx,
    const float* __restrict__ hbuf, const float* __restrict__ Wr1,
    const float* __restrict__ br1, const float* __restrict__ Wr2,
    float* __restrict__ agg, int E)
{
  __shared__ float sWr1[129 * 64];   // 33,024 B
  __shared__ float sWr2[64 * 384];   // 98,304 B
  __shared__ float sbr1[64];
  {
    const float4* s1 = (const float4*)Wr1; float4* d1 = (float4*)sWr1;
    for (int i = threadIdx.x; i < 129 * 64 / 4; i += blockDim.x) d1[i] = s1[i];
    const float4* s2 = (const float4*)Wr2; float4* d2 = (float4*)sWr2;
    for (int i = threadIdx.x; i < 64 * 384 / 4; i += blockDim.x) d2[i] = s2[i];
    if (threadIdx.x < 64) sbr1[threadIdx.x] = br1[threadIdx.x];
  }
  __syncthreads();
  const int l  = threadIdx.x & 63;
  const int gw = (int)((blockIdx.x * blockDim.x + threadIdx.x) >> 6);
  const int nw = (int)((gridDim.x * blockDim.x) >> 6);
  const int nch = (E + 7) >> 3;
  const float s3  = 1.7320508075688772f;
  const float s5  = 2.2360679774997896f;
  const float s15 = 3.872983346207417f;
  for (int ch = gw; ch < nch; ch += nw) {
    const int e0 = ch * 8;
    float ef_lo[8], ef_hi[8], len8[8];
#pragma unroll
    for (int e = 0; e < 8; ++e) {
      int ee = e0 + e; if (ee >= E) ee = E - 1;
      const float* p = edge_feats + (size_t)ee * 128;
      ef_lo[e] = p[l]; ef_hi[e] = p[64 + l];
      len8[e] = lengths[ee];
    }
    // layer 1: hidden unit = lane
    float z8[8];
    const float bb = sbr1[l];
#pragma unroll
    for (int e = 0; e < 8; ++e) z8[e] = bb;
    for (int c = 0; c < 64; ++c) {
      const float w = sWr1[c * 64 + l];
#pragma unroll
      for (int e = 0; e < 8; ++e) z8[e] = fmaf(rl_f(ef_lo[e], c), w, z8[e]);
    }
    for (int c = 0; c < 64; ++c) {
      const float w = sWr1[(64 + c) * 64 + l];
#pragma unroll
      for (int e = 0; e < 8; ++e) z8[e] = fmaf(rl_f(ef_hi[e], c), w, z8[e]);
    }
    {
      const float w = sWr1[128 * 64 + l];
#pragma unroll
      for (int e = 0; e < 8; ++e) z8[e] = fmaf(len8[e], w, z8[e]);
    }
#pragma unroll
    for (int e = 0; e < 8; ++e) {
      const float x = z8[e];
      z8[e] = x / (1.f + __expf(-x));     // silu
    }
    // layer 2: lane l owns outputs {l, 64+l, 128+l, ..., 320+l} -> R paths
    float a0[8], a1[8], a2[8], a3[8], a4[8], a5[8];
#pragma unroll
    for (int e = 0; e < 8; ++e) { a0[e]=0.f;a1[e]=0.f;a2[e]=0.f;a3[e]=0.f;a4[e]=0.f;a5[e]=0.f; }
    for (int hh = 0; hh < 64; ++hh) {
      const float* wr = sWr2 + hh * 384;
      const float w0_ = wr[l],       w1_ = wr[64 + l],  w2_ = wr[128 + l],
                  w3_ = wr[192 + l], w4_ = wr[256 + l], w5_ = wr[320 + l];
#pragma unroll
      for (int e = 0; e < 8; ++e) {
        const float zh = rl_f(z8[e], hh);
        a0[e] = fmaf(zh, w0_, a0[e]); a1[e] = fmaf(zh, w1_, a1[e]);
        a2[e] = fmaf(zh, w2_, a2[e]); a3[e] = fmaf(zh, w3_, a3[e]);
        a4[e] = fmaf(zh, w4_, a4[e]); a5[e] = fmaf(zh, w5_, a5[e]);
      }
    }
    // messages + scatter
#pragma unroll
    for (int e = 0; e < 8; ++e) {
      const int ee = e0 + e;
      if (ee >= E) break;
      const int snd = eidx[ee], rcv = eidx[E + ee];
      const float* hp = hbuf + (size_t)snd * 128;
      const float hs_lo = hp[l], hs_hi = hp[64 + l];
      const float vx = vectors[(size_t)ee * 3 + 0];
      const float vy = vectors[(size_t)ee * 3 + 1];
      const float vz = vectors[(size_t)ee * 3 + 2];
      const float inv = 1.f / (sqrtf(vx*vx + vy*vy + vz*vz) + 1e-9f);
      const float ux = vx * inv, uy = vy * inv, uz = vz * inv;
      const float Y1x = s3 * ux, Y1y = s3 * uy, Y1z = s3 * uz;
      const float Y20 = s15 * ux * uy, Y21 = s15 * uy * uz;
      const float Y22 = 0.5f * s5 * (3.f * uz * uz - 1.f);
      const float Y23 = s15 * ux * uz;
      const float Y24 = 0.5f * s15 * (ux * ux - uy * uy);
      const float r0lo = hs_lo * a0[e], r0hi = hs_hi * a1[e];
      const float r1lo = hs_lo * a2[e], r1hi = hs_hi * a3[e];
      const float r2lo = hs_lo * a4[e], r2hi = hs_hi * a5[e];
      float* base = agg + (size_t)rcv * 1152;
      atomicAdd(base + l,          r0lo);
      atomicAdd(base + 64 + l,     r0hi);
      atomicAdd(base + 128 + l,    r1lo * Y1x);
      atomicAdd(base + 192 + l,    r1hi * Y1x);
      atomicAdd(base + 256 + l,    r1lo * Y1y);
      atomicAdd(base + 320 + l,    r1hi * Y1y);
      atomicAdd(base + 384 + l,    r1lo * Y1z);
      atomicAdd(base + 448 + l,    r1hi * Y1z);
      atomicAdd(base + 512 + l,    r2lo * Y20);
      atomicAdd(base + 576 + l,    r2hi * Y20);
      atomicAdd(base + 640 + l,    r2lo * Y21);
      atomicAdd(base + 704 + l,    r2hi * Y21);
      atomicAdd(base + 768 + l,    r2lo * Y22);
      atomicAdd(base + 832 + l,    r2hi * Y22);
      atomicAdd(base + 896 + l,    r2lo * Y23);
      atomicAdd(base + 960 + l,    r2hi * Y23);
      atomicAdd(base + 1024 + l,   r2lo * Y24);
      atomicAdd(base + 1088 + l,   r2hi * Y24);
    }
  }
}

// ---------------- symmetric contraction (elementwise per n,d) --------------
__global__ __launch_bounds__(256) void k_contract(
    const float* __restrict__ svt, const float* __restrict__ w0,
    const float* __restrict__ w1, float* __restrict__ B, int Nn)
{
  const int gid = blockIdx.x * blockDim.x + threadIdx.x;
  if (gid >= Nn * 128) return;
  const int n = gid >> 7, d = gid & 127;
  const float* r = svt + (size_t)n * 1152 + d;
  const float s  = r[0];
  const float vx = r[128], vy = r[256], vz = r[384];
  const float ta = r[512], tb = r[640], tc = r[768], td = r[896], te = r[1024];
  const float c3 = tc * 0.5773502691896258f;      // c / sqrt(3)
  const float v2 = vx*vx + vy*vy + vz*vz;
  const float t2 = ta*ta + tb*tb + tc*tc + td*td + te*te;
  const float Tv0 = (te - c3) * vx + ta * vy + td * vz;
  const float Tv1 = ta * vx + (-te - c3) * vy + tb * vz;
  const float Tv2 = td * vx + tb * vy + 2.f * c3 * vz;
  const float vTv = vx * Tv0 + vy * Tv1 + vz * Tv2;
  const float s2 = s * s, s3v = s2 * s;
  const float B0 = s * w0[d] + s2 * w0[128 + d] + v2 * w0[256 + d] + t2 * w0[384 + d]
                 + s3v * w0[512 + d] + s * v2 * w0[640 + d] + s * t2 * w0[768 + d]
                 + vTv * w0[896 + d];
  const float k0 = w1[d],        k1 = w1[128 + d], k2 = w1[256 + d],
              k3 = w1[384 + d],  k4 = w1[512 + d], k5 = w1[640 + d];
  const float cv = k0 + s * k1 + s2 * k3 + v2 * k4;   // multiplies v
  const float cT = k2 + s * k5;                        // multiplies Tv
  float* ob = B + (size_t)n * 512;
  ob[d]        = B0;
  ob[128 + d]  = cv * vx + cT * Tv0;
  ob[256 + d]  = cv * vy + cT * Tv1;
  ob[384 + d]  = cv * vz + cT * Tv2;
}

// ---------------- readout + output assembly (wave per node) ----------------
__global__ __launch_bounds__(256) void k_readout(
    const float* __restrict__ h0buf, const float* __restrict__ h1buf,
    const float* __restrict__ W1, const float* __restrict__ b1,
    const float* __restrict__ W2, const float* __restrict__ W3,
    const float* __restrict__ wv,
    float* __restrict__ out0, float* __restrict__ out1, float* __restrict__ out2,
    int Nn)
{
  __shared__ float sW1[128 * 64];
  __shared__ float sW2[64 * 128];
  __shared__ float sb1[64];
  __shared__ float sW3[64];
  __shared__ float swv[128];
  {
    const float4* s1 = (const float4*)W1; float4* d1 = (float4*)sW1;
    for (int i = threadIdx.x; i < 128 * 64 / 4; i += blockDim.x) d1[i] = s1[i];
    const float4* s2 = (const float4*)W2; float4* d2 = (float4*)sW2;
    for (int i = threadIdx.x; i < 64 * 128 / 4; i += blockDim.x) d2[i] = s2[i];
    if (threadIdx.x < 64) { sb1[threadIdx.x] = b1[threadIdx.x]; sW3[threadIdx.x] = W3[threadIdx.x]; }
    if (threadIdx.x < 128) swv[threadIdx.x] = wv[threadIdx.x];
  }
  __syncthreads();
  const int l = threadIdx.x & 63;
  const int w = threadIdx.x >> 6;
  const int n = blockIdx.x * 4 + w;
  if (n >= Nn) return;
  const float h0_lo = h0buf[(size_t)n * 128 + l];
  const float h0_hi = h0buf[(size_t)n * 128 + 64 + l];
  const float* h1p = h1buf + (size_t)n * 384;          // layout [x][c]
  const float h1x_lo = h1p[l],       h1x_hi = h1p[64 + l];
  const float h1y_lo = h1p[128 + l], h1y_hi = h1p[192 + l];
  const float h1z_lo = h1p[256 + l], h1z_hi = h1p[320 + l];
  // z_j for j = lane
  float z = sb1[l];
  for (int c = 0; c < 64; ++c) z = fmaf(rl_f(h0_lo, c), sW1[c * 64 + l], z);
  for (int c = 0; c < 64; ++c) z = fmaf(rl_f(h0_hi, c), sW1[(64 + c) * 64 + l], z);
  z = z / (1.f + __expf(-z));                          // silu
  // gate = z @ W3  (wave reduction)
  float g = z * sW3[l];
  for (int off = 32; off >= 1; off >>= 1) g += __shfl_xor(g, off);
  // scal = z @ W2
  float sc_lo = 0.f, sc_hi = 0.f;
  for (int j = 0; j < 64; ++j) {
    const float zj = rl_f(z, j);
    sc_lo = fmaf(zj, sW2[j * 128 + l], sc_lo);
    sc_hi = fmaf(zj, sW2[j * 128 + 64 + l], sc_hi);
  }
  out0[(size_t)n * 128 + l]      = sc_lo;
  out0[(size_t)n * 128 + 64 + l] = sc_hi;
  // vec = (sum_c h1[c][x]*wv[c]) * gate
  float px = h1x_lo * swv[l] + h1x_hi * swv[64 + l];
  float py = h1y_lo * swv[l] + h1y_hi * swv[64 + l];
  float pz = h1z_lo * swv[l] + h1z_hi * swv[64 + l];
  for (int off = 32; off >= 1; off >>= 1) {
    px += __shfl_xor(px, off);
    py += __shfl_xor(py, off);
    pz += __shfl_xor(pz, off);
  }
  if (l == 0) {
    out1[(size_t)n * 3 + 0] = px * g;
    out1[(size_t)n * 3 + 1] = py * g;
    out1[(size_t)n * 3 + 2] = pz * g;
  }
  // node_feats_out = [h0 (128) | h1 interleaved c-major (c*3+x) (384)]
  float* o2 = out2 + (size_t)n * 512;
  o2[l]       = h0_lo;
  o2[64 + l]  = h0_hi;
  o2[128 + l * 3 + 0]        = h1x_lo;
  o2[128 + l * 3 + 1]        = h1y_lo;
  o2[128 + l * 3 + 2]        = h1z_lo;
  o2[128 + (64 + l) * 3 + 0] = h1x_hi;
  o2[128 + (64 + l) * 3 + 1] = h1y_hi;
  o2[128 + (64 + l) * 3 + 2] = h1z_hi;
}

// ---------------------------------------------------------------------------
extern "C" void kernel_launch(void* const* d_in, const int* in_sizes, int n_in,
                              void* d_out, int out_size, void* d_ws, size_t ws_size,
                              hipStream_t stream)
{
  const float* vectors    = (const float*)d_in[0];
  const float* lengths    = (const float*)d_in[1];
  const float* node_feats = (const float*)d_in[2];
  const float* edge_feats = (const float*)d_in[3];
  const int*   eidx       = (const int*)d_in[4];
  const float* W_up       = (const float*)d_in[5];
  const float* Wr1        = (const float*)d_in[6];
  const float* br1        = (const float*)d_in[7];
  const float* Wr2        = (const float*)d_in[8];
  const float* Wl0        = (const float*)d_in[9];
  const float* Wl1        = (const float*)d_in[10];
  const float* Wl2        = (const float*)d_in[11];
  const float* w0         = (const float*)d_in[12];
  const float* w1         = (const float*)d_in[13];
  const float* P0         = (const float*)d_in[14];
  const float* P1         = (const float*)d_in[15];
  const float* W1         = (const float*)d_in[16];
  const float* b1         = (const float*)d_in[17];
  const float* W2         = (const float*)d_in[18];
  const float* W3         = (const float*)d_in[19];
  const float* wv         = (const float*)d_in[20];

  const int N = in_sizes[2] / 128;   // 10000
  const int E = in_sizes[1];         // 160000 (lengths is [E,1])

  // workspace layout (floats). B/h0/h1 overlay agg (dead after svt GEMMs).
  float* hws  = (float*)d_ws;                    // N*128
  float* agg  = hws + (size_t)N * 128;           // N*1152
  float* svt  = agg + (size_t)N * 1152;          // N*1152
  float* Bws  = agg;                             // N*512
  float* h0ws = agg + (size_t)N * 512;           // N*128
  float* h1ws = agg + (size_t)N * 640;           // N*384

  hipMemsetAsync(agg, 0, (size_t)N * 1152 * sizeof(float), stream);

  // 1. h = node_feats @ W_up
  k_gemm128<<<512, 256, 0, stream>>>(node_feats, W_up, hws, N, 1, 128, 0, 128, 0, 1.f);

  // 2. edge MLP + messages + scatter
  k_edge<<<256, 256, 0, stream>>>(vectors, lengths, edge_feats, eidx, hws,
                                  Wr1, br1, Wr2, agg, E);

  // 3. s,v,t = (agg/16) @ Wl*
  const float inv_avg = 1.f / 16.f;
  k_gemm128<<<512, 256, 0, stream>>>(agg,        Wl0, svt,        N,     1, 1152, 0,   1152, 0,   inv_avg);
  k_gemm128<<<512, 256, 0, stream>>>(agg + 128,  Wl1, svt + 128,  3 * N, 3, 1152, 128, 1152, 128, inv_avg);
  k_gemm128<<<512, 256, 0, stream>>>(agg + 512,  Wl2, svt + 512,  5 * N, 5, 1152, 128, 1152, 128, inv_avg);

  // 4. symmetric contraction -> B0,B1
  k_contract<<<(N * 128 + 255) / 256, 256, 0, stream>>>(svt, w0, w1, Bws, N);

  // 5. h0 = B0 @ P0 ; h1 = B1 @ P1
  k_gemm128<<<512, 256, 0, stream>>>(Bws,       P0, h0ws, N,     1, 512, 0,   128, 0,   1.f);
  k_gemm128<<<512, 256, 0, stream>>>(Bws + 128, P1, h1ws, 3 * N, 3, 512, 128, 384, 128, 1.f);

  // 6. readout + outputs
  float* out0 = (float*)d_out;
  float* out1 = out0 + (size_t)N * 128;
  float* out2 = out1 + (size_t)N * 3;
  k_readout<<<(N + 3) / 4, 256, 0, stream>>>(h0ws, h1ws, W1, b1, W2, W3, wv,
                                             out0, out1, out2, N);
}

// Round 3
// 982.545 us; speedup vs baseline: 1.0549x; 1.0549x over previous
//
#include <hip/hip_runtime.h>
#include <math.h>

// ---------------------------------------------------------------------------
// MACE layer, f32. Round 2 (resubmit after broker timeout): occupancy fixes.
//   k_edge:    512-thread blocks (8 waves/CU, matches the 132-VGPR cap)
//   k_gemm128: 512-thread blocks, 64KB LDS -> 2 blocks/CU -> 16 waves/CU
//   k_readout: 512-thread blocks, 8 nodes/block
// Pipeline:
//   0. memset agg[N][9][128] = 0
//   1. h = node_feats @ W_up                      (k_gemm128)
//   2. per-edge radial MLP + messages + atomic scatter into agg   (k_edge)
//   3. s,v,t = (agg/16) @ {Wl0,Wl1,Wl2}           (k_gemm128 x3, batched rows)
//   4. symmetric contraction -> B0,B1             (k_contract, elementwise)
//   5. h0 = B0@P0 ; h1 = B1@P1                    (k_gemm128 x2)
//   6. readout: z=silu(h0@W1+b1), scal=z@W2, gate=z@W3, vec; write outputs
// ---------------------------------------------------------------------------

__device__ __forceinline__ float rl_f(float v, int lane) {
  // broadcast lane's value to all lanes (uniform index -> v_readlane -> SGPR)
  return __uint_as_float(__builtin_amdgcn_readlane(__float_as_uint(v), lane));
}

// ---------------- generic 128->128 GEMM: out = (scale*in) @ W --------------
// row r addressing: ptr = base + (r/gs)*nstride + (r%gs)*cstride
__global__ __launch_bounds__(512) void k_gemm128(
    const float* __restrict__ in, const float* __restrict__ W,
    float* __restrict__ out, int M, int gs,
    int nstride, int cstride, int onstride, int ocstride, float scale)
{
  __shared__ float sW[128 * 128];
  {
    const float4* src = (const float4*)W;
    float4* dst = (float4*)sW;
    for (int i = threadIdx.x; i < 128 * 128 / 4; i += blockDim.x) dst[i] = src[i];
  }
  __syncthreads();
  const int l  = threadIdx.x & 63;
  const int gw = (int)((blockIdx.x * blockDim.x + threadIdx.x) >> 6);
  const int nw = (int)((gridDim.x * blockDim.x) >> 6);
  const int nch = (M + 7) >> 3;
  for (int ch = gw; ch < nch; ch += nw) {
    const int r0 = ch * 8;
    float a_lo[8], a_hi[8], acc_lo[8], acc_hi[8];
#pragma unroll
    for (int e = 0; e < 8; ++e) {
      int r = r0 + e; if (r >= M) r = M - 1;
      const float* rp = in + (size_t)(r / gs) * nstride + (size_t)(r % gs) * cstride;
      a_lo[e] = rp[l] * scale;
      a_hi[e] = rp[64 + l] * scale;
      acc_lo[e] = 0.f; acc_hi[e] = 0.f;
    }
    for (int c = 0; c < 64; ++c) {
      const float w_lo = sW[c * 128 + l];
      const float w_hi = sW[c * 128 + 64 + l];
#pragma unroll
      for (int e = 0; e < 8; ++e) {
        const float a = rl_f(a_lo[e], c);
        acc_lo[e] = fmaf(a, w_lo, acc_lo[e]);
        acc_hi[e] = fmaf(a, w_hi, acc_hi[e]);
      }
    }
    for (int c = 0; c < 64; ++c) {
      const float w_lo = sW[(64 + c) * 128 + l];
      const float w_hi = sW[(64 + c) * 128 + 64 + l];
#pragma unroll
      for (int e = 0; e < 8; ++e) {
        const float a = rl_f(a_hi[e], c);
        acc_lo[e] = fmaf(a, w_lo, acc_lo[e]);
        acc_hi[e] = fmaf(a, w_hi, acc_hi[e]);
      }
    }
#pragma unroll
    for (int e = 0; e < 8; ++e) {
      const int r = r0 + e; if (r >= M) break;
      float* op = out + (size_t)(r / gs) * onstride + (size_t)(r % gs) * ocstride;
      op[l] = acc_lo[e];
      op[64 + l] = acc_hi[e];
    }
  }
}

// ---------------- edge kernel: radial MLP + messages + atomic scatter ------
__global__ __launch_bounds__(512) void k_edge(
    const float* __restrict__ vectors, const float* __restrict__ lengths,
    const float* __restrict__ edge_feats, const int* __restrict__ eidx,
    const float* __restrict__ hbuf, const float* __restrict__ Wr1,
    const float* __restrict__ br1, const float* __restrict__ Wr2,
    float* __restrict__ agg, int E)
{
  __shared__ float sWr1[129 * 64];   // 33,024 B
  __shared__ float sWr2[64 * 384];   // 98,304 B
  __shared__ float sbr1[64];
  {
    const float4* s1 = (const float4*)Wr1; float4* d1 = (float4*)sWr1;
    for (int i = threadIdx.x; i < 129 * 64 / 4; i += blockDim.x) d1[i] = s1[i];
    const float4* s2 = (const float4*)Wr2; float4* d2 = (float4*)sWr2;
    for (int i = threadIdx.x; i < 64 * 384 / 4; i += blockDim.x) d2[i] = s2[i];
    if (threadIdx.x < 64) sbr1[threadIdx.x] = br1[threadIdx.x];
  }
  __syncthreads();
  const int l  = threadIdx.x & 63;
  const int gw = (int)((blockIdx.x * blockDim.x + threadIdx.x) >> 6);
  const int nw = (int)((gridDim.x * blockDim.x) >> 6);
  const int nch = (E + 7) >> 3;
  const float s3  = 1.7320508075688772f;
  const float s5  = 2.2360679774997896f;
  const float s15 = 3.872983346207417f;
  for (int ch = gw; ch < nch; ch += nw) {
    const int e0 = ch * 8;
    float ef_lo[8], ef_hi[8], len8[8];
#pragma unroll
    for (int e = 0; e < 8; ++e) {
      int ee = e0 + e; if (ee >= E) ee = E - 1;
      const float* p = edge_feats + (size_t)ee * 128;
      ef_lo[e] = p[l]; ef_hi[e] = p[64 + l];
      len8[e] = lengths[ee];
    }
    // layer 1: hidden unit = lane
    float z8[8];
    const float bb = sbr1[l];
#pragma unroll
    for (int e = 0; e < 8; ++e) z8[e] = bb;
    for (int c = 0; c < 64; ++c) {
      const float w = sWr1[c * 64 + l];
#pragma unroll
      for (int e = 0; e < 8; ++e) z8[e] = fmaf(rl_f(ef_lo[e], c), w, z8[e]);
    }
    for (int c = 0; c < 64; ++c) {
      const float w = sWr1[(64 + c) * 64 + l];
#pragma unroll
      for (int e = 0; e < 8; ++e) z8[e] = fmaf(rl_f(ef_hi[e], c), w, z8[e]);
    }
    {
      const float w = sWr1[128 * 64 + l];
#pragma unroll
      for (int e = 0; e < 8; ++e) z8[e] = fmaf(len8[e], w, z8[e]);
    }
#pragma unroll
    for (int e = 0; e < 8; ++e) {
      const float x = z8[e];
      z8[e] = x / (1.f + __expf(-x));     // silu
    }
    // layer 2: lane l owns outputs {l, 64+l, 128+l, ..., 320+l} -> R paths
    float a0[8], a1[8], a2[8], a3[8], a4[8], a5[8];
#pragma unroll
    for (int e = 0; e < 8; ++e) { a0[e]=0.f;a1[e]=0.f;a2[e]=0.f;a3[e]=0.f;a4[e]=0.f;a5[e]=0.f; }
    for (int hh = 0; hh < 64; ++hh) {
      const float* wr = sWr2 + hh * 384;
      const float w0_ = wr[l],       w1_ = wr[64 + l],  w2_ = wr[128 + l],
                  w3_ = wr[192 + l], w4_ = wr[256 + l], w5_ = wr[320 + l];
#pragma unroll
      for (int e = 0; e < 8; ++e) {
        const float zh = rl_f(z8[e], hh);
        a0[e] = fmaf(zh, w0_, a0[e]); a1[e] = fmaf(zh, w1_, a1[e]);
        a2[e] = fmaf(zh, w2_, a2[e]); a3[e] = fmaf(zh, w3_, a3[e]);
        a4[e] = fmaf(zh, w4_, a4[e]); a5[e] = fmaf(zh, w5_, a5[e]);
      }
    }
    // messages + scatter
#pragma unroll
    for (int e = 0; e < 8; ++e) {
      const int ee = e0 + e;
      if (ee >= E) break;
      const int snd = eidx[ee], rcv = eidx[E + ee];
      const float* hp = hbuf + (size_t)snd * 128;
      const float hs_lo = hp[l], hs_hi = hp[64 + l];
      const float vx = vectors[(size_t)ee * 3 + 0];
      const float vy = vectors[(size_t)ee * 3 + 1];
      const float vz = vectors[(size_t)ee * 3 + 2];
      const float inv = 1.f / (sqrtf(vx*vx + vy*vy + vz*vz) + 1e-9f);
      const float ux = vx * inv, uy = vy * inv, uz = vz * inv;
      const float Y1x = s3 * ux, Y1y = s3 * uy, Y1z = s3 * uz;
      const float Y20 = s15 * ux * uy, Y21 = s15 * uy * uz;
      const float Y22 = 0.5f * s5 * (3.f * uz * uz - 1.f);
      const float Y23 = s15 * ux * uz;
      const float Y24 = 0.5f * s15 * (ux * ux - uy * uy);
      const float r0lo = hs_lo * a0[e], r0hi = hs_hi * a1[e];
      const float r1lo = hs_lo * a2[e], r1hi = hs_hi * a3[e];
      const float r2lo = hs_lo * a4[e], r2hi = hs_hi * a5[e];
      float* base = agg + (size_t)rcv * 1152;
      atomicAdd(base + l,          r0lo);
      atomicAdd(base + 64 + l,     r0hi);
      atomicAdd(base + 128 + l,    r1lo * Y1x);
      atomicAdd(base + 192 + l,    r1hi * Y1x);
      atomicAdd(base + 256 + l,    r1lo * Y1y);
      atomicAdd(base + 320 + l,    r1hi * Y1y);
      atomicAdd(base + 384 + l,    r1lo * Y1z);
      atomicAdd(base + 448 + l,    r1hi * Y1z);
      atomicAdd(base + 512 + l,    r2lo * Y20);
      atomicAdd(base + 576 + l,    r2hi * Y20);
      atomicAdd(base + 640 + l,    r2lo * Y21);
      atomicAdd(base + 704 + l,    r2hi * Y21);
      atomicAdd(base + 768 + l,    r2lo * Y22);
      atomicAdd(base + 832 + l,    r2hi * Y22);
      atomicAdd(base + 896 + l,    r2lo * Y23);
      atomicAdd(base + 960 + l,    r2hi * Y23);
      atomicAdd(base + 1024 + l,   r2lo * Y24);
      atomicAdd(base + 1088 + l,   r2hi * Y24);
    }
  }
}

// ---------------- symmetric contraction (elementwise per n,d) --------------
__global__ __launch_bounds__(256) void k_contract(
    const float* __restrict__ svt, const float* __restrict__ w0,
    const float* __restrict__ w1, float* __restrict__ B, int Nn)
{
  const int gid = blockIdx.x * blockDim.x + threadIdx.x;
  if (gid >= Nn * 128) return;
  const int n = gid >> 7, d = gid & 127;
  const float* r = svt + (size_t)n * 1152 + d;
  const float s  = r[0];
  const float vx = r[128], vy = r[256], vz = r[384];
  const float ta = r[512], tb = r[640], tc = r[768], td = r[896], te = r[1024];
  const float c3 = tc * 0.5773502691896258f;      // c / sqrt(3)
  const float v2 = vx*vx + vy*vy + vz*vz;
  const float t2 = ta*ta + tb*tb + tc*tc + td*td + te*te;
  const float Tv0 = (te - c3) * vx + ta * vy + td * vz;
  const float Tv1 = ta * vx + (-te - c3) * vy + tb * vz;
  const float Tv2 = td * vx + tb * vy + 2.f * c3 * vz;
  const float vTv = vx * Tv0 + vy * Tv1 + vz * Tv2;
  const float s2 = s * s, s3v = s2 * s;
  const float B0 = s * w0[d] + s2 * w0[128 + d] + v2 * w0[256 + d] + t2 * w0[384 + d]
                 + s3v * w0[512 + d] + s * v2 * w0[640 + d] + s * t2 * w0[768 + d]
                 + vTv * w0[896 + d];
  const float k0 = w1[d],        k1 = w1[128 + d], k2 = w1[256 + d],
              k3 = w1[384 + d],  k4 = w1[512 + d], k5 = w1[640 + d];
  const float cv = k0 + s * k1 + s2 * k3 + v2 * k4;   // multiplies v
  const float cT = k2 + s * k5;                        // multiplies Tv
  float* ob = B + (size_t)n * 512;
  ob[d]        = B0;
  ob[128 + d]  = cv * vx + cT * Tv0;
  ob[256 + d]  = cv * vy + cT * Tv1;
  ob[384 + d]  = cv * vz + cT * Tv2;
}

// ---------------- readout + output assembly (wave per node) ----------------
__global__ __launch_bounds__(512) void k_readout(
    const float* __restrict__ h0buf, const float* __restrict__ h1buf,
    const float* __restrict__ W1, const float* __restrict__ b1,
    const float* __restrict__ W2, const float* __restrict__ W3,
    const float* __restrict__ wv,
    float* __restrict__ out0, float* __restrict__ out1, float* __restrict__ out2,
    int Nn)
{
  __shared__ float sW1[128 * 64];
  __shared__ float sW2[64 * 128];
  __shared__ float sb1[64];
  __shared__ float sW3[64];
  __shared__ float swv[128];
  {
    const float4* s1 = (const float4*)W1; float4* d1 = (float4*)sW1;
    for (int i = threadIdx.x; i < 128 * 64 / 4; i += blockDim.x) d1[i] = s1[i];
    const float4* s2 = (const float4*)W2; float4* d2 = (float4*)sW2;
    for (int i = threadIdx.x; i < 64 * 128 / 4; i += blockDim.x) d2[i] = s2[i];
    if (threadIdx.x < 64) { sb1[threadIdx.x] = b1[threadIdx.x]; sW3[threadIdx.x] = W3[threadIdx.x]; }
    if (threadIdx.x < 128) swv[threadIdx.x] = wv[threadIdx.x];
  }
  __syncthreads();
  const int l = threadIdx.x & 63;
  const int w = threadIdx.x >> 6;
  const int n = blockIdx.x * 8 + w;
  if (n >= Nn) return;
  const float h0_lo = h0buf[(size_t)n * 128 + l];
  const float h0_hi = h0buf[(size_t)n * 128 + 64 + l];
  const float* h1p = h1buf + (size_t)n * 384;          // layout [x][c]
  const float h1x_lo = h1p[l],       h1x_hi = h1p[64 + l];
  const float h1y_lo = h1p[128 + l], h1y_hi = h1p[192 + l];
  const float h1z_lo = h1p[256 + l], h1z_hi = h1p[320 + l];
  // z_j for j = lane
  float z = sb1[l];
  for (int c = 0; c < 64; ++c) z = fmaf(rl_f(h0_lo, c), sW1[c * 64 + l], z);
  for (int c = 0; c < 64; ++c) z = fmaf(rl_f(h0_hi, c), sW1[(64 + c) * 64 + l], z);
  z = z / (1.f + __expf(-z));                          // silu
  // gate = z @ W3  (wave reduction)
  float g = z * sW3[l];
  for (int off = 32; off >= 1; off >>= 1) g += __shfl_xor(g, off);
  // scal = z @ W2
  float sc_lo = 0.f, sc_hi = 0.f;
  for (int j = 0; j < 64; ++j) {
    const float zj = rl_f(z, j);
    sc_lo = fmaf(zj, sW2[j * 128 + l], sc_lo);
    sc_hi = fmaf(zj, sW2[j * 128 + 64 + l], sc_hi);
  }
  out0[(size_t)n * 128 + l]      = sc_lo;
  out0[(size_t)n * 128 + 64 + l] = sc_hi;
  // vec = (sum_c h1[c][x]*wv[c]) * gate
  float px = h1x_lo * swv[l] + h1x_hi * swv[64 + l];
  float py = h1y_lo * swv[l] + h1y_hi * swv[64 + l];
  float pz = h1z_lo * swv[l] + h1z_hi * swv[64 + l];
  for (int off = 32; off >= 1; off >>= 1) {
    px += __shfl_xor(px, off);
    py += __shfl_xor(py, off);
    pz += __shfl_xor(pz, off);
  }
  if (l == 0) {
    out1[(size_t)n * 3 + 0] = px * g;
    out1[(size_t)n * 3 + 1] = py * g;
    out1[(size_t)n * 3 + 2] = pz * g;
  }
  // node_feats_out = [h0 (128) | h1 interleaved c-major (c*3+x) (384)]
  float* o2 = out2 + (size_t)n * 512;
  o2[l]       = h0_lo;
  o2[64 + l]  = h0_hi;
  o2[128 + l * 3 + 0]        = h1x_lo;
  o2[128 + l * 3 + 1]        = h1y_lo;
  o2[128 + l * 3 + 2]        = h1z_lo;
  o2[128 + (64 + l) * 3 + 0] = h1x_hi;
  o2[128 + (64 + l) * 3 + 1] = h1y_hi;
  o2[128 + (64 + l) * 3 + 2] = h1z_hi;
}

// ---------------------------------------------------------------------------
extern "C" void kernel_launch(void* const* d_in, const int* in_sizes, int n_in,
                              void* d_out, int out_size, void* d_ws, size_t ws_size,
                              hipStream_t stream)
{
  const float* vectors    = (const float*)d_in[0];
  const float* lengths    = (const float*)d_in[1];
  const float* node_feats = (const float*)d_in[2];
  const float* edge_feats = (const float*)d_in[3];
  const int*   eidx       = (const int*)d_in[4];
  const float* W_up       = (const float*)d_in[5];
  const float* Wr1        = (const float*)d_in[6];
  const float* br1        = (const float*)d_in[7];
  const float* Wr2        = (const float*)d_in[8];
  const float* Wl0        = (const float*)d_in[9];
  const float* Wl1        = (const float*)d_in[10];
  const float* Wl2        = (const float*)d_in[11];
  const float* w0         = (const float*)d_in[12];
  const float* w1         = (const float*)d_in[13];
  const float* P0         = (const float*)d_in[14];
  const float* P1         = (const float*)d_in[15];
  const float* W1         = (const float*)d_in[16];
  const float* b1         = (const float*)d_in[17];
  const float* W2         = (const float*)d_in[18];
  const float* W3         = (const float*)d_in[19];
  const float* wv         = (const float*)d_in[20];

  const int N = in_sizes[2] / 128;   // 10000
  const int E = in_sizes[1];         // 160000 (lengths is [E,1])

  // workspace layout (floats). B/h0/h1 overlay agg (dead after svt GEMMs).
  float* hws  = (float*)d_ws;                    // N*128
  float* agg  = hws + (size_t)N * 128;           // N*1152
  float* svt  = agg + (size_t)N * 1152;          // N*1152
  float* Bws  = agg;                             // N*512
  float* h0ws = agg + (size_t)N * 512;           // N*128
  float* h1ws = agg + (size_t)N * 640;           // N*384

  hipMemsetAsync(agg, 0, (size_t)N * 1152 * sizeof(float), stream);

  // 1. h = node_feats @ W_up
  k_gemm128<<<512, 512, 0, stream>>>(node_feats, W_up, hws, N, 1, 128, 0, 128, 0, 1.f);

  // 2. edge MLP + messages + scatter
  k_edge<<<256, 512, 0, stream>>>(vectors, lengths, edge_feats, eidx, hws,
                                  Wr1, br1, Wr2, agg, E);

  // 3. s,v,t = (agg/16) @ Wl*
  const float inv_avg = 1.f / 16.f;
  k_gemm128<<<512, 512, 0, stream>>>(agg,        Wl0, svt,        N,     1, 1152, 0,   1152, 0,   inv_avg);
  k_gemm128<<<512, 512, 0, stream>>>(agg + 128,  Wl1, svt + 128,  3 * N, 3, 1152, 128, 1152, 128, inv_avg);
  k_gemm128<<<512, 512, 0, stream>>>(agg + 512,  Wl2, svt + 512,  5 * N, 5, 1152, 128, 1152, 128, inv_avg);

  // 4. symmetric contraction -> B0,B1
  k_contract<<<(N * 128 + 255) / 256, 256, 0, stream>>>(svt, w0, w1, Bws, N);

  // 5. h0 = B0 @ P0 ; h1 = B1 @ P1
  k_gemm128<<<512, 512, 0, stream>>>(Bws,       P0, h0ws, N,     1, 512, 0,   128, 0,   1.f);
  k_gemm128<<<512, 512, 0, stream>>>(Bws + 128, P1, h1ws, 3 * N, 3, 512, 128, 384, 128, 1.f);

  // 6. readout + outputs
  float* out0 = (float*)d_out;
  float* out1 = out0 + (size_t)N * 128;
  float* out2 = out1 + (size_t)N * 3;
  k_readout<<<(N + 7) / 8, 512, 0, stream>>>(h0ws, h1ws, W1, b1, W2, W3, wv,
                                             out0, out1, out2, N);
}

// Round 6
// 796.679 us; speedup vs baseline: 1.3011x; 1.2333x over previous
//
#include <hip/hip_runtime.h>
#include <math.h>

// ---------------------------------------------------------------------------
// MACE layer, f32. Round 4 (resubmit #2 after broker timeouts): kill the
// atomic scatter. Round-3 counters: k_edge WRITE_SIZE=720MB == full per-edge
// message traffic; agg (46MB) >> L2 (4MB/XCD) so every atomicAdd was an HBM
// RMW. Fix: counting sort edges by receiver, then wave-per-receiver
// accumulation in registers, one plain store per agg row (0 atomics hot).
// Pipeline:
//   0. memset counts/cnt2 (80KB)
//   1. k_hist / k_scan / k_scatter : receiver-sorted edge permutation
//   2. h = node_feats @ W_up                      (k_gemm128)
//   3. k_edge_sorted: radial MLP + messages, register segment-sum, store agg
//   4. s,v,t = (agg/16) @ {Wl0,Wl1,Wl2}           (k_gemm128 x3)
//   5. symmetric contraction -> B0,B1             (k_contract)
//   6. h0 = B0@P0 ; h1 = B1@P1                    (k_gemm128 x2)
//   7. readout
// ---------------------------------------------------------------------------

__device__ __forceinline__ float rl_f(float v, int lane) {
  return __uint_as_float(__builtin_amdgcn_readlane(__float_as_uint(v), lane));
}

// ---------------- counting sort: histogram / scan / scatter ----------------
__global__ __launch_bounds__(512) void k_hist(const int* __restrict__ eidx,
                                              int* __restrict__ counts, int E) {
  const int i = blockIdx.x * blockDim.x + threadIdx.x;
  if (i < E) atomicAdd(&counts[eidx[E + i]], 1);
}

__global__ __launch_bounds__(1024) void k_scan(const int* __restrict__ counts,
                                               int* __restrict__ offs, int Nn) {
  __shared__ int part[1024];
  const int t = threadIdx.x;
  const int CH = (Nn + 1023) >> 10;
  int s = 0;
  for (int i = 0; i < CH; ++i) {
    const int idx = t * CH + i;
    if (idx < Nn) s += counts[idx];
  }
  part[t] = s; __syncthreads();
  for (int off = 1; off < 1024; off <<= 1) {
    int v = (t >= off) ? part[t - off] : 0;
    __syncthreads();
    part[t] += v;
    __syncthreads();
  }
  int excl = (t == 0) ? 0 : part[t - 1];
  for (int i = 0; i < CH; ++i) {
    const int idx = t * CH + i;
    if (idx < Nn) { offs[idx] = excl; excl += counts[idx]; }
  }
  if (t == 1023) offs[Nn] = part[1023];
}

__global__ __launch_bounds__(512) void k_scatter(const int* __restrict__ eidx,
                                                 const int* __restrict__ offs,
                                                 int* __restrict__ cnt2,
                                                 int* __restrict__ perm, int E) {
  const int i = blockIdx.x * blockDim.x + threadIdx.x;
  if (i < E) {
    const int r = eidx[E + i];
    const int p = offs[r] + atomicAdd(&cnt2[r], 1);
    perm[p] = i;
  }
}

// ---------------- generic 128->128 GEMM: out = (scale*in) @ W --------------
__global__ __launch_bounds__(512) void k_gemm128(
    const float* __restrict__ in, const float* __restrict__ W,
    float* __restrict__ out, int M, int gs,
    int nstride, int cstride, int onstride, int ocstride, float scale)
{
  __shared__ float sW[128 * 128];
  {
    const float4* src = (const float4*)W;
    float4* dst = (float4*)sW;
    for (int i = threadIdx.x; i < 128 * 128 / 4; i += blockDim.x) dst[i] = src[i];
  }
  __syncthreads();
  const int l  = threadIdx.x & 63;
  const int gw = (int)((blockIdx.x * blockDim.x + threadIdx.x) >> 6);
  const int nw = (int)((gridDim.x * blockDim.x) >> 6);
  const int nch = (M + 7) >> 3;
  for (int ch = gw; ch < nch; ch += nw) {
    const int r0 = ch * 8;
    float a_lo[8], a_hi[8], acc_lo[8], acc_hi[8];
#pragma unroll
    for (int e = 0; e < 8; ++e) {
      int r = r0 + e; if (r >= M) r = M - 1;
      const float* rp = in + (size_t)(r / gs) * nstride + (size_t)(r % gs) * cstride;
      a_lo[e] = rp[l] * scale;
      a_hi[e] = rp[64 + l] * scale;
      acc_lo[e] = 0.f; acc_hi[e] = 0.f;
    }
    for (int c = 0; c < 64; ++c) {
      const float w_lo = sW[c * 128 + l];
      const float w_hi = sW[c * 128 + 64 + l];
#pragma unroll
      for (int e = 0; e < 8; ++e) {
        const float a = rl_f(a_lo[e], c);
        acc_lo[e] = fmaf(a, w_lo, acc_lo[e]);
        acc_hi[e] = fmaf(a, w_hi, acc_hi[e]);
      }
    }
    for (int c = 0; c < 64; ++c) {
      const float w_lo = sW[(64 + c) * 128 + l];
      const float w_hi = sW[(64 + c) * 128 + 64 + l];
#pragma unroll
      for (int e = 0; e < 8; ++e) {
        const float a = rl_f(a_hi[e], c);
        acc_lo[e] = fmaf(a, w_lo, acc_lo[e]);
        acc_hi[e] = fmaf(a, w_hi, acc_hi[e]);
      }
    }
#pragma unroll
    for (int e = 0; e < 8; ++e) {
      const int r = r0 + e; if (r >= M) break;
      float* op = out + (size_t)(r / gs) * onstride + (size_t)(r % gs) * ocstride;
      op[l] = acc_lo[e];
      op[64 + l] = acc_hi[e];
    }
  }
}

// ------- edge kernel: wave per receiver, register segment accumulation -----
__global__ __launch_bounds__(512) void k_edge_sorted(
    const float* __restrict__ vectors, const float* __restrict__ lengths,
    const float* __restrict__ edge_feats, const int* __restrict__ eidx,
    const int* __restrict__ perm, const int* __restrict__ offs,
    const float* __restrict__ hbuf, const float* __restrict__ Wr1,
    const float* __restrict__ br1, const float* __restrict__ Wr2,
    float* __restrict__ agg, int Nn)
{
  __shared__ float sWr1[129 * 64];   // 33,024 B
  __shared__ float sWr2[64 * 384];   // 98,304 B
  __shared__ float sbr1[64];
  {
    const float4* s1 = (const float4*)Wr1; float4* d1 = (float4*)sWr1;
    for (int i = threadIdx.x; i < 129 * 64 / 4; i += blockDim.x) d1[i] = s1[i];
    const float4* s2 = (const float4*)Wr2; float4* d2 = (float4*)sWr2;
    for (int i = threadIdx.x; i < 64 * 384 / 4; i += blockDim.x) d2[i] = s2[i];
    if (threadIdx.x < 64) sbr1[threadIdx.x] = br1[threadIdx.x];
  }
  __syncthreads();
  const int l  = threadIdx.x & 63;
  const int gw = (int)((blockIdx.x * blockDim.x + threadIdx.x) >> 6);
  const int nw = (int)((gridDim.x * blockDim.x) >> 6);
  const float s3  = 1.7320508075688772f;
  const float s5  = 2.2360679774997896f;
  const float s15 = 3.872983346207417f;
  for (int r = gw; r < Nn; r += nw) {
    float acc[18];
#pragma unroll
    for (int k = 0; k < 18; ++k) acc[k] = 0.f;
    const int beg = offs[r], end = offs[r + 1];
    for (int b = beg; b < end; b += 8) {
      const int cnt = (end - b < 8) ? (end - b) : 8;
      int ee8[8];
      float ef_lo[8], ef_hi[8], len8[8];
#pragma unroll
      for (int e = 0; e < 8; ++e) {
        const int ee = perm[b + (e < cnt ? e : cnt - 1)];
        ee8[e] = ee;
        const float* p = edge_feats + (size_t)ee * 128;
        ef_lo[e] = p[l]; ef_hi[e] = p[64 + l];
        len8[e] = lengths[ee];
      }
      // layer 1: hidden unit = lane
      float z8[8];
      const float bb = sbr1[l];
#pragma unroll
      for (int e = 0; e < 8; ++e) z8[e] = bb;
      for (int c = 0; c < 64; ++c) {
        const float w = sWr1[c * 64 + l];
#pragma unroll
        for (int e = 0; e < 8; ++e) z8[e] = fmaf(rl_f(ef_lo[e], c), w, z8[e]);
      }
      for (int c = 0; c < 64; ++c) {
        const float w = sWr1[(64 + c) * 64 + l];
#pragma unroll
        for (int e = 0; e < 8; ++e) z8[e] = fmaf(rl_f(ef_hi[e], c), w, z8[e]);
      }
      {
        const float w = sWr1[128 * 64 + l];
#pragma unroll
        for (int e = 0; e < 8; ++e) z8[e] = fmaf(len8[e], w, z8[e]);
      }
#pragma unroll
      for (int e = 0; e < 8; ++e) {
        const float x = z8[e];
        z8[e] = x / (1.f + __expf(-x));     // silu
      }
      // layer 2: lane l owns R-path outputs {l, 64+l, ..., 320+l}
      float a0[8], a1[8], a2[8], a3[8], a4[8], a5[8];
#pragma unroll
      for (int e = 0; e < 8; ++e) { a0[e]=0.f;a1[e]=0.f;a2[e]=0.f;a3[e]=0.f;a4[e]=0.f;a5[e]=0.f; }
      for (int hh = 0; hh < 64; ++hh) {
        const float* wr = sWr2 + hh * 384;
        const float w0_ = wr[l],       w1_ = wr[64 + l],  w2_ = wr[128 + l],
                    w3_ = wr[192 + l], w4_ = wr[256 + l], w5_ = wr[320 + l];
#pragma unroll
        for (int e = 0; e < 8; ++e) {
          const float zh = rl_f(z8[e], hh);
          a0[e] = fmaf(zh, w0_, a0[e]); a1[e] = fmaf(zh, w1_, a1[e]);
          a2[e] = fmaf(zh, w2_, a2[e]); a3[e] = fmaf(zh, w3_, a3[e]);
          a4[e] = fmaf(zh, w4_, a4[e]); a5[e] = fmaf(zh, w5_, a5[e]);
        }
      }
      // accumulate messages for this receiver (registers, no atomics)
#pragma unroll
      for (int e = 0; e < 8; ++e) {
        if (e >= cnt) break;
        const int ee = ee8[e];
        const int snd = eidx[ee];
        const float* hp = hbuf + (size_t)snd * 128;
        const float hs_lo = hp[l], hs_hi = hp[64 + l];
        const float vx = vectors[(size_t)ee * 3 + 0];
        const float vy = vectors[(size_t)ee * 3 + 1];
        const float vz = vectors[(size_t)ee * 3 + 2];
        const float inv = 1.f / (sqrtf(vx*vx + vy*vy + vz*vz) + 1e-9f);
        const float ux = vx * inv, uy = vy * inv, uz = vz * inv;
        const float Y1x = s3 * ux, Y1y = s3 * uy, Y1z = s3 * uz;
        const float Y20 = s15 * ux * uy, Y21 = s15 * uy * uz;
        const float Y22 = 0.5f * s5 * (3.f * uz * uz - 1.f);
        const float Y23 = s15 * ux * uz;
        const float Y24 = 0.5f * s15 * (ux * ux - uy * uy);
        const float r0lo = hs_lo * a0[e], r0hi = hs_hi * a1[e];
        const float r1lo = hs_lo * a2[e], r1hi = hs_hi * a3[e];
        const float r2lo = hs_lo * a4[e], r2hi = hs_hi * a5[e];
        acc[0]  += r0lo;        acc[1]  += r0hi;
        acc[2]  += r1lo * Y1x;  acc[3]  += r1hi * Y1x;
        acc[4]  += r1lo * Y1y;  acc[5]  += r1hi * Y1y;
        acc[6]  += r1lo * Y1z;  acc[7]  += r1hi * Y1z;
        acc[8]  += r2lo * Y20;  acc[9]  += r2hi * Y20;
        acc[10] += r2lo * Y21;  acc[11] += r2hi * Y21;
        acc[12] += r2lo * Y22;  acc[13] += r2hi * Y22;
        acc[14] += r2lo * Y23;  acc[15] += r2hi * Y23;
        acc[16] += r2lo * Y24;  acc[17] += r2hi * Y24;
      }
    }
    float* base = agg + (size_t)r * 1152;
#pragma unroll
    for (int k = 0; k < 18; ++k) base[k * 64 + l] = acc[k];
  }
}

// ---------------- symmetric contraction (elementwise per n,d) --------------
__global__ __launch_bounds__(256) void k_contract(
    const float* __restrict__ svt, const float* __restrict__ w0,
    const float* __restrict__ w1, float* __restrict__ B, int Nn)
{
  const int gid = blockIdx.x * blockDim.x + threadIdx.x;
  if (gid >= Nn * 128) return;
  const int n = gid >> 7, d = gid & 127;
  const float* r = svt + (size_t)n * 1152 + d;
  const float s  = r[0];
  const float vx = r[128], vy = r[256], vz = r[384];
  const float ta = r[512], tb = r[640], tc = r[768], td = r[896], te = r[1024];
  const float c3 = tc * 0.5773502691896258f;      // c / sqrt(3)
  const float v2 = vx*vx + vy*vy + vz*vz;
  const float t2 = ta*ta + tb*tb + tc*tc + td*td + te*te;
  const float Tv0 = (te - c3) * vx + ta * vy + td * vz;
  const float Tv1 = ta * vx + (-te - c3) * vy + tb * vz;
  const float Tv2 = td * vx + tb * vy + 2.f * c3 * vz;
  const float vTv = vx * Tv0 + vy * Tv1 + vz * Tv2;
  const float s2 = s * s, s3v = s2 * s;
  const float B0 = s * w0[d] + s2 * w0[128 + d] + v2 * w0[256 + d] + t2 * w0[384 + d]
                 + s3v * w0[512 + d] + s * v2 * w0[640 + d] + s * t2 * w0[768 + d]
                 + vTv * w0[896 + d];
  const float k0 = w1[d],        k1 = w1[128 + d], k2 = w1[256 + d],
              k3 = w1[384 + d],  k4 = w1[512 + d], k5 = w1[640 + d];
  const float cv = k0 + s * k1 + s2 * k3 + v2 * k4;   // multiplies v
  const float cT = k2 + s * k5;                        // multiplies Tv
  float* ob = B + (size_t)n * 512;
  ob[d]        = B0;
  ob[128 + d]  = cv * vx + cT * Tv0;
  ob[256 + d]  = cv * vy + cT * Tv1;
  ob[384 + d]  = cv * vz + cT * Tv2;
}

// ---------------- readout + output assembly (wave per node) ----------------
__global__ __launch_bounds__(512) void k_readout(
    const float* __restrict__ h0buf, const float* __restrict__ h1buf,
    const float* __restrict__ W1, const float* __restrict__ b1,
    const float* __restrict__ W2, const float* __restrict__ W3,
    const float* __restrict__ wv,
    float* __restrict__ out0, float* __restrict__ out1, float* __restrict__ out2,
    int Nn)
{
  __shared__ float sW1[128 * 64];
  __shared__ float sW2[64 * 128];
  __shared__ float sb1[64];
  __shared__ float sW3[64];
  __shared__ float swv[128];
  {
    const float4* s1 = (const float4*)W1; float4* d1 = (float4*)sW1;
    for (int i = threadIdx.x; i < 128 * 64 / 4; i += blockDim.x) d1[i] = s1[i];
    const float4* s2 = (const float4*)W2; float4* d2 = (float4*)sW2;
    for (int i = threadIdx.x; i < 64 * 128 / 4; i += blockDim.x) d2[i] = s2[i];
    if (threadIdx.x < 64) { sb1[threadIdx.x] = b1[threadIdx.x]; sW3[threadIdx.x] = W3[threadIdx.x]; }
    if (threadIdx.x < 128) swv[threadIdx.x] = wv[threadIdx.x];
  }
  __syncthreads();
  const int l = threadIdx.x & 63;
  const int w = threadIdx.x >> 6;
  const int n = blockIdx.x * 8 + w;
  if (n >= Nn) return;
  const float h0_lo = h0buf[(size_t)n * 128 + l];
  const float h0_hi = h0buf[(size_t)n * 128 + 64 + l];
  const float* h1p = h1buf + (size_t)n * 384;          // layout [x][c]
  const float h1x_lo = h1p[l],       h1x_hi = h1p[64 + l];
  const float h1y_lo = h1p[128 + l], h1y_hi = h1p[192 + l];
  const float h1z_lo = h1p[256 + l], h1z_hi = h1p[320 + l];
  float z = sb1[l];
  for (int c = 0; c < 64; ++c) z = fmaf(rl_f(h0_lo, c), sW1[c * 64 + l], z);
  for (int c = 0; c < 64; ++c) z = fmaf(rl_f(h0_hi, c), sW1[(64 + c) * 64 + l], z);
  z = z / (1.f + __expf(-z));                          // silu
  float g = z * sW3[l];
  for (int off = 32; off >= 1; off >>= 1) g += __shfl_xor(g, off);
  float sc_lo = 0.f, sc_hi = 0.f;
  for (int j = 0; j < 64; ++j) {
    const float zj = rl_f(z, j);
    sc_lo = fmaf(zj, sW2[j * 128 + l], sc_lo);
    sc_hi = fmaf(zj, sW2[j * 128 + 64 + l], sc_hi);
  }
  out0[(size_t)n * 128 + l]      = sc_lo;
  out0[(size_t)n * 128 + 64 + l] = sc_hi;
  float px = h1x_lo * swv[l] + h1x_hi * swv[64 + l];
  float py = h1y_lo * swv[l] + h1y_hi * swv[64 + l];
  float pz = h1z_lo * swv[l] + h1z_hi * swv[64 + l];
  for (int off = 32; off >= 1; off >>= 1) {
    px += __shfl_xor(px, off);
    py += __shfl_xor(py, off);
    pz += __shfl_xor(pz, off);
  }
  if (l == 0) {
    out1[(size_t)n * 3 + 0] = px * g;
    out1[(size_t)n * 3 + 1] = py * g;
    out1[(size_t)n * 3 + 2] = pz * g;
  }
  float* o2 = out2 + (size_t)n * 512;
  o2[l]       = h0_lo;
  o2[64 + l]  = h0_hi;
  o2[128 + l * 3 + 0]        = h1x_lo;
  o2[128 + l * 3 + 1]        = h1y_lo;
  o2[128 + l * 3 + 2]        = h1z_lo;
  o2[128 + (64 + l) * 3 + 0] = h1x_hi;
  o2[128 + (64 + l) * 3 + 1] = h1y_hi;
  o2[128 + (64 + l) * 3 + 2] = h1z_hi;
}

// ---------------------------------------------------------------------------
extern "C" void kernel_launch(void* const* d_in, const int* in_sizes, int n_in,
                              void* d_out, int out_size, void* d_ws, size_t ws_size,
                              hipStream_t stream)
{
  const float* vectors    = (const float*)d_in[0];
  const float* lengths    = (const float*)d_in[1];
  const float* node_feats = (const float*)d_in[2];
  const float* edge_feats = (const float*)d_in[3];
  const int*   eidx       = (const int*)d_in[4];
  const float* W_up       = (const float*)d_in[5];
  const float* Wr1        = (const float*)d_in[6];
  const float* br1        = (const float*)d_in[7];
  const float* Wr2        = (const float*)d_in[8];
  const float* Wl0        = (const float*)d_in[9];
  const float* Wl1        = (const float*)d_in[10];
  const float* Wl2        = (const float*)d_in[11];
  const float* w0         = (const float*)d_in[12];
  const float* w1         = (const float*)d_in[13];
  const float* P0         = (const float*)d_in[14];
  const float* P1         = (const float*)d_in[15];
  const float* W1         = (const float*)d_in[16];
  const float* b1         = (const float*)d_in[17];
  const float* W2         = (const float*)d_in[18];
  const float* W3         = (const float*)d_in[19];
  const float* wv         = (const float*)d_in[20];

  const int N = in_sizes[2] / 128;   // 10000
  const int E = in_sizes[1];         // 160000 (lengths is [E,1])

  // workspace layout (floats). B/h0/h1 overlay agg; sort ints overlay svt
  // (svt is only written after the edge kernel, when the sort data is dead).
  float* hws  = (float*)d_ws;                    // N*128
  float* agg  = hws + (size_t)N * 128;           // N*1152
  float* svt  = agg + (size_t)N * 1152;          // N*1152
  float* Bws  = agg;                             // N*512
  float* h0ws = agg + (size_t)N * 512;           // N*128
  float* h1ws = agg + (size_t)N * 640;           // N*384
  int*   counts = (int*)svt;                     // N
  int*   cnt2   = counts + N;                    // N
  int*   offs   = cnt2 + N;                      // N+1
  int*   perm   = offs + N + 1;                  // E

  // 0. zero the sort counters (counts + cnt2 adjacent)
  hipMemsetAsync(counts, 0, (size_t)2 * N * sizeof(int), stream);

  // 1. receiver-sorted edge permutation
  k_hist<<<(E + 511) / 512, 512, 0, stream>>>(eidx, counts, E);
  k_scan<<<1, 1024, 0, stream>>>(counts, offs, N);
  k_scatter<<<(E + 511) / 512, 512, 0, stream>>>(eidx, offs, cnt2, perm, E);

  // 2. h = node_feats @ W_up
  k_gemm128<<<512, 512, 0, stream>>>(node_feats, W_up, hws, N, 1, 128, 0, 128, 0, 1.f);

  // 3. edge MLP + register segment-sum (no atomics, no agg memset needed)
  k_edge_sorted<<<256, 512, 0, stream>>>(vectors, lengths, edge_feats, eidx,
                                         perm, offs, hws, Wr1, br1, Wr2, agg, N);

  // 4. s,v,t = (agg/16) @ Wl*
  const float inv_avg = 1.f / 16.f;
  k_gemm128<<<512, 512, 0, stream>>>(agg,        Wl0, svt,        N,     1, 1152, 0,   1152, 0,   inv_avg);
  k_gemm128<<<512, 512, 0, stream>>>(agg + 128,  Wl1, svt + 128,  3 * N, 3, 1152, 128, 1152, 128, inv_avg);
  k_gemm128<<<512, 512, 0, stream>>>(agg + 512,  Wl2, svt + 512,  5 * N, 5, 1152, 128, 1152, 128, inv_avg);

  // 5. symmetric contraction -> B0,B1
  k_contract<<<(N * 128 + 255) / 256, 256, 0, stream>>>(svt, w0, w1, Bws, N);

  // 6. h0 = B0 @ P0 ; h1 = B1 @ P1
  k_gemm128<<<512, 512, 0, stream>>>(Bws,       P0, h0ws, N,     1, 512, 0,   128, 0,   1.f);
  k_gemm128<<<512, 512, 0, stream>>>(Bws + 128, P1, h1ws, 3 * N, 3, 512, 128, 384, 128, 1.f);

  // 7. readout + outputs
  float* out0 = (float*)d_out;
  float* out1 = out0 + (size_t)N * 128;
  float* out2 = out1 + (size_t)N * 3;
  k_readout<<<(N + 7) / 8, 512, 0, stream>>>(h0ws, h1ws, W1, b1, W2, W3, wv,
                                             out0, out1, out2, N);
}

// Round 16
// 528.777 us; speedup vs baseline: 1.9602x; 1.5066x over previous
//
#include <hip/hip_runtime.h>
#include <math.h>

// ---------------------------------------------------------------------------
// MACE layer. Round 7 (resubmit #9 after infra failures): radial MLP on
// matrix cores.
//   k_mlp: bf16 MFMA (16x16x32) edge MLP over sorted edge order -> Rb[E,384]
//   k_msg: wave-per-receiver gather (sequential Rb reads) + register seg-sum
// Node GEMMs (k_gemm128 f32) unchanged this round; fallback to round-4
// integrated k_edge_sorted if ws_size is too small for Rb.
// ---------------------------------------------------------------------------

typedef __attribute__((ext_vector_type(8))) short bf16x8;
typedef __attribute__((ext_vector_type(4))) float f32x4;

__device__ __forceinline__ float rl_f(float v, int lane) {
  return __uint_as_float(__builtin_amdgcn_readlane(__float_as_uint(v), lane));
}
__device__ __forceinline__ unsigned short f2bf(float x) {
  unsigned u = __float_as_uint(x);
  return (unsigned short)((u + 0x7FFFu + ((u >> 16) & 1u)) >> 16);  // RNE
}
__device__ __forceinline__ float bf2f(unsigned short b) {
  return __uint_as_float(((unsigned)b) << 16);
}

// ---------------- counting sort: histogram / scan / scatter ----------------
__global__ __launch_bounds__(512) void k_hist(const int* __restrict__ eidx,
                                              int* __restrict__ counts, int E) {
  const int i = blockIdx.x * blockDim.x + threadIdx.x;
  if (i < E) atomicAdd(&counts[eidx[E + i]], 1);
}

__global__ __launch_bounds__(1024) void k_scan(const int* __restrict__ counts,
                                               int* __restrict__ offs, int Nn) {
  __shared__ int part[1024];
  const int t = threadIdx.x;
  const int CH = (Nn + 1023) >> 10;
  int s = 0;
  for (int i = 0; i < CH; ++i) {
    const int idx = t * CH + i;
    if (idx < Nn) s += counts[idx];
  }
  part[t] = s; __syncthreads();
  for (int off = 1; off < 1024; off <<= 1) {
    int v = (t >= off) ? part[t - off] : 0;
    __syncthreads();
    part[t] += v;
    __syncthreads();
  }
  int excl = (t == 0) ? 0 : part[t - 1];
  for (int i = 0; i < CH; ++i) {
    const int idx = t * CH + i;
    if (idx < Nn) { offs[idx] = excl; excl += counts[idx]; }
  }
  if (t == 1023) offs[Nn] = part[1023];
}

__global__ __launch_bounds__(512) void k_scatter(const int* __restrict__ eidx,
                                                 const int* __restrict__ offs,
                                                 int* __restrict__ cnt2,
                                                 int* __restrict__ perm, int E) {
  const int i = blockIdx.x * blockDim.x + threadIdx.x;
  if (i < E) {
    const int r = eidx[E + i];
    const int p = offs[r] + atomicAdd(&cnt2[r], 1);
    perm[p] = i;
  }
}

// ---------------- generic 128->128 GEMM: out = (scale*in) @ W --------------
__global__ __launch_bounds__(512) void k_gemm128(
    const float* __restrict__ in, const float* __restrict__ W,
    float* __restrict__ out, int M, int gs,
    int nstride, int cstride, int onstride, int ocstride, float scale)
{
  __shared__ float sW[128 * 128];
  {
    const float4* src = (const float4*)W;
    float4* dst = (float4*)sW;
    for (int i = threadIdx.x; i < 128 * 128 / 4; i += blockDim.x) dst[i] = src[i];
  }
  __syncthreads();
  const int l  = threadIdx.x & 63;
  const int gw = (int)((blockIdx.x * blockDim.x + threadIdx.x) >> 6);
  const int nw = (int)((gridDim.x * blockDim.x) >> 6);
  const int nch = (M + 7) >> 3;
  for (int ch = gw; ch < nch; ch += nw) {
    const int r0 = ch * 8;
    float a_lo[8], a_hi[8], acc_lo[8], acc_hi[8];
#pragma unroll
    for (int e = 0; e < 8; ++e) {
      int r = r0 + e; if (r >= M) r = M - 1;
      const float* rp = in + (size_t)(r / gs) * nstride + (size_t)(r % gs) * cstride;
      a_lo[e] = rp[l] * scale;
      a_hi[e] = rp[64 + l] * scale;
      acc_lo[e] = 0.f; acc_hi[e] = 0.f;
    }
    for (int c = 0; c < 64; ++c) {
      const float w_lo = sW[c * 128 + l];
      const float w_hi = sW[c * 128 + 64 + l];
#pragma unroll
      for (int e = 0; e < 8; ++e) {
        const float a = rl_f(a_lo[e], c);
        acc_lo[e] = fmaf(a, w_lo, acc_lo[e]);
        acc_hi[e] = fmaf(a, w_hi, acc_hi[e]);
      }
    }
    for (int c = 0; c < 64; ++c) {
      const float w_lo = sW[(64 + c) * 128 + l];
      const float w_hi = sW[(64 + c) * 128 + 64 + l];
#pragma unroll
      for (int e = 0; e < 8; ++e) {
        const float a = rl_f(a_hi[e], c);
        acc_lo[e] = fmaf(a, w_lo, acc_lo[e]);
        acc_hi[e] = fmaf(a, w_hi, acc_hi[e]);
      }
    }
#pragma unroll
    for (int e = 0; e < 8; ++e) {
      const int r = r0 + e; if (r >= M) break;
      float* op = out + (size_t)(r / gs) * onstride + (size_t)(r % gs) * ocstride;
      op[l] = acc_lo[e];
      op[64 + l] = acc_hi[e];
    }
  }
}

// ---------------- MFMA edge MLP: Rb[sorted_pos][384] = bf16(R) -------------
// tile = 16 edges (sorted order) per wave; weights bf16-transposed in LDS.
#define MLP_WAVES 8
__global__ __launch_bounds__(512) void k_mlp(
    const float* __restrict__ edge_feats, const float* __restrict__ lengths,
    const int* __restrict__ perm,
    const float* __restrict__ Wr1, const float* __restrict__ br1,
    const float* __restrict__ Wr2,
    unsigned short* __restrict__ Rb, int E)
{
  __shared__ __align__(16) unsigned short sW1T[64 * 136];   // [n][k<=128], stride 136
  __shared__ __align__(16) unsigned short sW2T[384 * 72];   // [n][k<64],  stride 72
  __shared__ float sb1[64];
  __shared__ float sw128[64];
  __shared__ __align__(16) unsigned short zbuf[MLP_WAVES][16 * 72]; // z [m][k], stride 72
  for (int i = threadIdx.x; i < 64 * 128; i += 512) {
    const int k = i >> 6, n = i & 63;            // Wr1[k][n] coalesced in n
    sW1T[n * 136 + k] = f2bf(Wr1[i]);
  }
  for (int i = threadIdx.x; i < 64 * 384; i += 512) {
    const int k = i / 384, n = i % 384;          // Wr2[k][n]
    sW2T[n * 72 + k] = f2bf(Wr2[i]);
  }
  if (threadIdx.x < 64) {
    sb1[threadIdx.x]   = br1[threadIdx.x];
    sw128[threadIdx.x] = Wr1[128 * 64 + threadIdx.x];
  }
  __syncthreads();

  const int l   = threadIdx.x & 63;
  const int m16 = l & 15;          // A-row (edge) / B-col selector
  const int g   = l >> 4;          // k-group (8 elems each)
  const int wid = threadIdx.x >> 6;
  const int ntile = E >> 4;        // E is a multiple of 16

  for (int t = blockIdx.x * MLP_WAVES + wid; t < ntile; t += gridDim.x * MLP_WAVES) {
    const int e0 = t * 16;
    // ---- A fragments (edge_feats rows, bf16) ----
    const int peA = perm[e0 + m16];
    const float* rp = edge_feats + (size_t)peA * 128 + g * 8;
    bf16x8 afr[4];
#pragma unroll
    for (int kb = 0; kb < 4; ++kb) {
      const float4 v0 = *(const float4*)(rp + kb * 32);
      const float4 v1 = *(const float4*)(rp + kb * 32 + 4);
      bf16x8 a;
      a[0] = (short)f2bf(v0.x); a[1] = (short)f2bf(v0.y);
      a[2] = (short)f2bf(v0.z); a[3] = (short)f2bf(v0.w);
      a[4] = (short)f2bf(v1.x); a[5] = (short)f2bf(v1.y);
      a[6] = (short)f2bf(v1.z); a[7] = (short)f2bf(v1.w);
      afr[kb] = a;
    }
    // ---- rows this lane owns in C layout ----
    int pe_c[4]; float len_c[4];
#pragma unroll
    for (int r = 0; r < 4; ++r) {
      pe_c[r] = perm[e0 + g * 4 + r];
      len_c[r] = lengths[pe_c[r]];
    }
    // ---- GEMM1 -> z (silu), staged to per-wave LDS transpose buffer ----
    unsigned short* zw = zbuf[wid];
#pragma unroll
    for (int nt = 0; nt < 4; ++nt) {
      f32x4 acc = {0.f, 0.f, 0.f, 0.f};
#pragma unroll
      for (int kb = 0; kb < 4; ++kb) {
        const bf16x8 b = *(const bf16x8*)(sW1T + (nt * 16 + m16) * 136 + kb * 32 + g * 8);
        acc = __builtin_amdgcn_mfma_f32_16x16x32_bf16(afr[kb], b, acc, 0, 0, 0);
      }
      const int n = nt * 16 + m16;
      const float bias = sb1[n], wlen = sw128[n];
#pragma unroll
      for (int r = 0; r < 4; ++r) {
        float x = acc[r] + bias + len_c[r] * wlen;
        x = x / (1.f + __expf(-x));                 // silu
        zw[(g * 4 + r) * 72 + n] = f2bf(x);
      }
    }
    // ---- GEMM2: R = z @ Wr2 ----
    bf16x8 zfr0 = *(const bf16x8*)(zw + m16 * 72 + g * 8);
    bf16x8 zfr1 = *(const bf16x8*)(zw + m16 * 72 + 32 + g * 8);
    unsigned short* outp = Rb + (size_t)e0 * 384;
#pragma unroll
    for (int nt = 0; nt < 24; ++nt) {
      f32x4 acc = {0.f, 0.f, 0.f, 0.f};
      const bf16x8 b0 = *(const bf16x8*)(sW2T + (nt * 16 + m16) * 72 + g * 8);
      const bf16x8 b1 = *(const bf16x8*)(sW2T + (nt * 16 + m16) * 72 + 32 + g * 8);
      acc = __builtin_amdgcn_mfma_f32_16x16x32_bf16(zfr0, b0, acc, 0, 0, 0);
      acc = __builtin_amdgcn_mfma_f32_16x16x32_bf16(zfr1, b1, acc, 0, 0, 0);
      const int n = nt * 16 + m16;
#pragma unroll
      for (int r = 0; r < 4; ++r)
        outp[(size_t)(g * 4 + r) * 384 + n] = f2bf(acc[r]);
    }
  }
}

// -------- message gather + register segment-sum (wave per receiver) --------
__global__ __launch_bounds__(256) void k_msg(
    const float* __restrict__ vectors, const int* __restrict__ eidx,
    const int* __restrict__ perm, const int* __restrict__ offs,
    const unsigned short* __restrict__ Rb, const float* __restrict__ hbuf,
    float* __restrict__ agg, int Nn, int E)
{
  const int l  = threadIdx.x & 63;
  const int gw = (int)((blockIdx.x * blockDim.x + threadIdx.x) >> 6);
  const int nw = (int)((gridDim.x * blockDim.x) >> 6);
  const float s3  = 1.7320508075688772f;
  const float s5  = 2.2360679774997896f;
  const float s15 = 3.872983346207417f;
  for (int r = gw; r < Nn; r += nw) {
    float acc[18];
#pragma unroll
    for (int k = 0; k < 18; ++k) acc[k] = 0.f;
    const int beg = offs[r], end = offs[r + 1];
    for (int idx = beg; idx < end; ++idx) {
      const int e = perm[idx];
      const int snd = eidx[e];
      const float* hp = hbuf + (size_t)snd * 128;
      const float hs_lo = hp[l], hs_hi = hp[64 + l];
      const unsigned short* Rp = Rb + (size_t)idx * 384;
      const float a0 = bf2f(Rp[l]),        a1 = bf2f(Rp[64 + l]);
      const float a2 = bf2f(Rp[128 + l]),  a3 = bf2f(Rp[192 + l]);
      const float a4 = bf2f(Rp[256 + l]),  a5 = bf2f(Rp[320 + l]);
      const float vx = vectors[(size_t)e * 3 + 0];
      const float vy = vectors[(size_t)e * 3 + 1];
      const float vz = vectors[(size_t)e * 3 + 2];
      const float inv = 1.f / (sqrtf(vx * vx + vy * vy + vz * vz) + 1e-9f);
      const float ux = vx * inv, uy = vy * inv, uz = vz * inv;
      const float Y1x = s3 * ux, Y1y = s3 * uy, Y1z = s3 * uz;
      const float Y20 = s15 * ux * uy, Y21 = s15 * uy * uz;
      const float Y22 = 0.5f * s5 * (3.f * uz * uz - 1.f);
      const float Y23 = s15 * ux * uz;
      const float Y24 = 0.5f * s15 * (ux * ux - uy * uy);
      const float r0lo = hs_lo * a0, r0hi = hs_hi * a1;
      const float r1lo = hs_lo * a2, r1hi = hs_hi * a3;
      const float r2lo = hs_lo * a4, r2hi = hs_hi * a5;
      acc[0]  += r0lo;        acc[1]  += r0hi;
      acc[2]  += r1lo * Y1x;  acc[3]  += r1hi * Y1x;
      acc[4]  += r1lo * Y1y;  acc[5]  += r1hi * Y1y;
      acc[6]  += r1lo * Y1z;  acc[7]  += r1hi * Y1z;
      acc[8]  += r2lo * Y20;  acc[9]  += r2hi * Y20;
      acc[10] += r2lo * Y21;  acc[11] += r2hi * Y21;
      acc[12] += r2lo * Y22;  acc[13] += r2hi * Y22;
      acc[14] += r2lo * Y23;  acc[15] += r2hi * Y23;
      acc[16] += r2lo * Y24;  acc[17] += r2hi * Y24;
    }
    float* base = agg + (size_t)r * 1152;
#pragma unroll
    for (int k = 0; k < 18; ++k) base[k * 64 + l] = acc[k];
  }
}

// ------- fallback: round-4 integrated edge kernel (readlane MLP) -----------
__global__ __launch_bounds__(512) void k_edge_sorted(
    const float* __restrict__ vectors, const float* __restrict__ lengths,
    const float* __restrict__ edge_feats, const int* __restrict__ eidx,
    const int* __restrict__ perm, const int* __restrict__ offs,
    const float* __restrict__ hbuf, const float* __restrict__ Wr1,
    const float* __restrict__ br1, const float* __restrict__ Wr2,
    float* __restrict__ agg, int Nn)
{
  __shared__ float sWr1[129 * 64];
  __shared__ float sWr2[64 * 384];
  __shared__ float sbr1[64];
  {
    const float4* s1 = (const float4*)Wr1; float4* d1 = (float4*)sWr1;
    for (int i = threadIdx.x; i < 129 * 64 / 4; i += blockDim.x) d1[i] = s1[i];
    const float4* s2 = (const float4*)Wr2; float4* d2 = (float4*)sWr2;
    for (int i = threadIdx.x; i < 64 * 384 / 4; i += blockDim.x) d2[i] = s2[i];
    if (threadIdx.x < 64) sbr1[threadIdx.x] = br1[threadIdx.x];
  }
  __syncthreads();
  const int l  = threadIdx.x & 63;
  const int gw = (int)((blockIdx.x * blockDim.x + threadIdx.x) >> 6);
  const int nw = (int)((gridDim.x * blockDim.x) >> 6);
  const float s3  = 1.7320508075688772f;
  const float s5  = 2.2360679774997896f;
  const float s15 = 3.872983346207417f;
  for (int r = gw; r < Nn; r += nw) {
    float acc[18];
#pragma unroll
    for (int k = 0; k < 18; ++k) acc[k] = 0.f;
    const int beg = offs[r], end = offs[r + 1];
    for (int b = beg; b < end; b += 8) {
      const int cnt = (end - b < 8) ? (end - b) : 8;
      int ee8[8];
      float ef_lo[8], ef_hi[8], len8[8];
#pragma unroll
      for (int e = 0; e < 8; ++e) {
        const int ee = perm[b + (e < cnt ? e : cnt - 1)];
        ee8[e] = ee;
        const float* p = edge_feats + (size_t)ee * 128;
        ef_lo[e] = p[l]; ef_hi[e] = p[64 + l];
        len8[e] = lengths[ee];
      }
      float z8[8];
      const float bb = sbr1[l];
#pragma unroll
      for (int e = 0; e < 8; ++e) z8[e] = bb;
      for (int c = 0; c < 64; ++c) {
        const float w = sWr1[c * 64 + l];
#pragma unroll
        for (int e = 0; e < 8; ++e) z8[e] = fmaf(rl_f(ef_lo[e], c), w, z8[e]);
      }
      for (int c = 0; c < 64; ++c) {
        const float w = sWr1[(64 + c) * 64 + l];
#pragma unroll
        for (int e = 0; e < 8; ++e) z8[e] = fmaf(rl_f(ef_hi[e], c), w, z8[e]);
      }
      {
        const float w = sWr1[128 * 64 + l];
#pragma unroll
        for (int e = 0; e < 8; ++e) z8[e] = fmaf(len8[e], w, z8[e]);
      }
#pragma unroll
      for (int e = 0; e < 8; ++e) {
        const float x = z8[e];
        z8[e] = x / (1.f + __expf(-x));
      }
      float a0[8], a1[8], a2[8], a3[8], a4[8], a5[8];
#pragma unroll
      for (int e = 0; e < 8; ++e) { a0[e]=0.f;a1[e]=0.f;a2[e]=0.f;a3[e]=0.f;a4[e]=0.f;a5[e]=0.f; }
      for (int hh = 0; hh < 64; ++hh) {
        const float* wr = sWr2 + hh * 384;
        const float w0_ = wr[l],       w1_ = wr[64 + l],  w2_ = wr[128 + l],
                    w3_ = wr[192 + l], w4_ = wr[256 + l], w5_ = wr[320 + l];
#pragma unroll
        for (int e = 0; e < 8; ++e) {
          const float zh = rl_f(z8[e], hh);
          a0[e] = fmaf(zh, w0_, a0[e]); a1[e] = fmaf(zh, w1_, a1[e]);
          a2[e] = fmaf(zh, w2_, a2[e]); a3[e] = fmaf(zh, w3_, a3[e]);
          a4[e] = fmaf(zh, w4_, a4[e]); a5[e] = fmaf(zh, w5_, a5[e]);
        }
      }
#pragma unroll
      for (int e = 0; e < 8; ++e) {
        if (e >= cnt) break;
        const int ee = ee8[e];
        const int snd = eidx[ee];
        const float* hp = hbuf + (size_t)snd * 128;
        const float hs_lo = hp[l], hs_hi = hp[64 + l];
        const float vx = vectors[(size_t)ee * 3 + 0];
        const float vy = vectors[(size_t)ee * 3 + 1];
        const float vz = vectors[(size_t)ee * 3 + 2];
        const float inv = 1.f / (sqrtf(vx*vx + vy*vy + vz*vz) + 1e-9f);
        const float ux = vx * inv, uy = vy * inv, uz = vz * inv;
        const float Y1x = s3 * ux, Y1y = s3 * uy, Y1z = s3 * uz;
        const float Y20 = s15 * ux * uy, Y21 = s15 * uy * uz;
        const float Y22 = 0.5f * s5 * (3.f * uz * uz - 1.f);
        const float Y23 = s15 * ux * uz;
        const float Y24 = 0.5f * s15 * (ux * ux - uy * uy);
        const float r0lo = hs_lo * a0[e], r0hi = hs_hi * a1[e];
        const float r1lo = hs_lo * a2[e], r1hi = hs_hi * a3[e];
        const float r2lo = hs_lo * a4[e], r2hi = hs_hi * a5[e];
        acc[0]  += r0lo;        acc[1]  += r0hi;
        acc[2]  += r1lo * Y1x;  acc[3]  += r1hi * Y1x;
        acc[4]  += r1lo * Y1y;  acc[5]  += r1hi * Y1y;
        acc[6]  += r1lo * Y1z;  acc[7]  += r1hi * Y1z;
        acc[8]  += r2lo * Y20;  acc[9]  += r2hi * Y20;
        acc[10] += r2lo * Y21;  acc[11] += r2hi * Y21;
        acc[12] += r2lo * Y22;  acc[13] += r2hi * Y22;
        acc[14] += r2lo * Y23;  acc[15] += r2hi * Y23;
        acc[16] += r2lo * Y24;  acc[17] += r2hi * Y24;
      }
    }
    float* base = agg + (size_t)r * 1152;
#pragma unroll
    for (int k = 0; k < 18; ++k) base[k * 64 + l] = acc[k];
  }
}

// ---------------- symmetric contraction (elementwise per n,d) --------------
__global__ __launch_bounds__(256) void k_contract(
    const float* __restrict__ svt, const float* __restrict__ w0,
    const float* __restrict__ w1, float* __restrict__ B, int Nn)
{
  const int gid = blockIdx.x * blockDim.x + threadIdx.x;
  if (gid >= Nn * 128) return;
  const int n = gid >> 7, d = gid & 127;
  const float* r = svt + (size_t)n * 1152 + d;
  const float s  = r[0];
  const float vx = r[128], vy = r[256], vz = r[384];
  const float ta = r[512], tb = r[640], tc = r[768], td = r[896], te = r[1024];
  const float c3 = tc * 0.5773502691896258f;
  const float v2 = vx*vx + vy*vy + vz*vz;
  const float t2 = ta*ta + tb*tb + tc*tc + td*td + te*te;
  const float Tv0 = (te - c3) * vx + ta * vy + td * vz;
  const float Tv1 = ta * vx + (-te - c3) * vy + tb * vz;
  const float Tv2 = td * vx + tb * vy + 2.f * c3 * vz;
  const float vTv = vx * Tv0 + vy * Tv1 + vz * Tv2;
  const float s2 = s * s, s3v = s2 * s;
  const float B0 = s * w0[d] + s2 * w0[128 + d] + v2 * w0[256 + d] + t2 * w0[384 + d]
                 + s3v * w0[512 + d] + s * v2 * w0[640 + d] + s * t2 * w0[768 + d]
                 + vTv * w0[896 + d];
  const float k0 = w1[d],        k1 = w1[128 + d], k2 = w1[256 + d],
              k3 = w1[384 + d],  k4 = w1[512 + d], k5 = w1[640 + d];
  const float cv = k0 + s * k1 + s2 * k3 + v2 * k4;
  const float cT = k2 + s * k5;
  float* ob = B + (size_t)n * 512;
  ob[d]        = B0;
  ob[128 + d]  = cv * vx + cT * Tv0;
  ob[256 + d]  = cv * vy + cT * Tv1;
  ob[384 + d]  = cv * vz + cT * Tv2;
}

// ---------------- readout + output assembly (wave per node) ----------------
__global__ __launch_bounds__(512) void k_readout(
    const float* __restrict__ h0buf, const float* __restrict__ h1buf,
    const float* __restrict__ W1, const float* __restrict__ b1,
    const float* __restrict__ W2, const float* __restrict__ W3,
    const float* __restrict__ wv,
    float* __restrict__ out0, float* __restrict__ out1, float* __restrict__ out2,
    int Nn)
{
  __shared__ float sW1[128 * 64];
  __shared__ float sW2[64 * 128];
  __shared__ float sb1[64];
  __shared__ float sW3[64];
  __shared__ float swv[128];
  {
    const float4* s1 = (const float4*)W1; float4* d1 = (float4*)sW1;
    for (int i = threadIdx.x; i < 128 * 64 / 4; i += blockDim.x) d1[i] = s1[i];
    const float4* s2 = (const float4*)W2; float4* d2 = (float4*)sW2;
    for (int i = threadIdx.x; i < 64 * 128 / 4; i += blockDim.x) d2[i] = s2[i];
    if (threadIdx.x < 64) { sb1[threadIdx.x] = b1[threadIdx.x]; sW3[threadIdx.x] = W3[threadIdx.x]; }
    if (threadIdx.x < 128) swv[threadIdx.x] = wv[threadIdx.x];
  }
  __syncthreads();
  const int l = threadIdx.x & 63;
  const int w = threadIdx.x >> 6;
  const int n = blockIdx.x * 8 + w;
  if (n >= Nn) return;
  const float h0_lo = h0buf[(size_t)n * 128 + l];
  const float h0_hi = h0buf[(size_t)n * 128 + 64 + l];
  const float* h1p = h1buf + (size_t)n * 384;
  const float h1x_lo = h1p[l],       h1x_hi = h1p[64 + l];
  const float h1y_lo = h1p[128 + l], h1y_hi = h1p[192 + l];
  const float h1z_lo = h1p[256 + l], h1z_hi = h1p[320 + l];
  float z = sb1[l];
  for (int c = 0; c < 64; ++c) z = fmaf(rl_f(h0_lo, c), sW1[c * 64 + l], z);
  for (int c = 0; c < 64; ++c) z = fmaf(rl_f(h0_hi, c), sW1[(64 + c) * 64 + l], z);
  z = z / (1.f + __expf(-z));
  float g = z * sW3[l];
  for (int off = 32; off >= 1; off >>= 1) g += __shfl_xor(g, off);
  float sc_lo = 0.f, sc_hi = 0.f;
  for (int j = 0; j < 64; ++j) {
    const float zj = rl_f(z, j);
    sc_lo = fmaf(zj, sW2[j * 128 + l], sc_lo);
    sc_hi = fmaf(zj, sW2[j * 128 + 64 + l], sc_hi);
  }
  out0[(size_t)n * 128 + l]      = sc_lo;
  out0[(size_t)n * 128 + 64 + l] = sc_hi;
  float px = h1x_lo * swv[l] + h1x_hi * swv[64 + l];
  float py = h1y_lo * swv[l] + h1y_hi * swv[64 + l];
  float pz = h1z_lo * swv[l] + h1z_hi * swv[64 + l];
  for (int off = 32; off >= 1; off >>= 1) {
    px += __shfl_xor(px, off);
    py += __shfl_xor(py, off);
    pz += __shfl_xor(pz, off);
  }
  if (l == 0) {
    out1[(size_t)n * 3 + 0] = px * g;
    out1[(size_t)n * 3 + 1] = py * g;
    out1[(size_t)n * 3 + 2] = pz * g;
  }
  float* o2 = out2 + (size_t)n * 512;
  o2[l]       = h0_lo;
  o2[64 + l]  = h0_hi;
  o2[128 + l * 3 + 0]        = h1x_lo;
  o2[128 + l * 3 + 1]        = h1y_lo;
  o2[128 + l * 3 + 2]        = h1z_lo;
  o2[128 + (64 + l) * 3 + 0] = h1x_hi;
  o2[128 + (64 + l) * 3 + 1] = h1y_hi;
  o2[128 + (64 + l) * 3 + 2] = h1z_hi;
}

// ---------------------------------------------------------------------------
extern "C" void kernel_launch(void* const* d_in, const int* in_sizes, int n_in,
                              void* d_out, int out_size, void* d_ws, size_t ws_size,
                              hipStream_t stream)
{
  const float* vectors    = (const float*)d_in[0];
  const float* lengths    = (const float*)d_in[1];
  const float* node_feats = (const float*)d_in[2];
  const float* edge_feats = (const float*)d_in[3];
  const int*   eidx       = (const int*)d_in[4];
  const float* W_up       = (const float*)d_in[5];
  const float* Wr1        = (const float*)d_in[6];
  const float* br1        = (const float*)d_in[7];
  const float* Wr2        = (const float*)d_in[8];
  const float* Wl0        = (const float*)d_in[9];
  const float* Wl1        = (const float*)d_in[10];
  const float* Wl2        = (const float*)d_in[11];
  const float* w0         = (const float*)d_in[12];
  const float* w1         = (const float*)d_in[13];
  const float* P0         = (const float*)d_in[14];
  const float* P1         = (const float*)d_in[15];
  const float* W1         = (const float*)d_in[16];
  const float* b1         = (const float*)d_in[17];
  const float* W2         = (const float*)d_in[18];
  const float* W3         = (const float*)d_in[19];
  const float* wv         = (const float*)d_in[20];

  const int N = in_sizes[2] / 128;   // 10000
  const int E = in_sizes[1];         // 160000

  const size_t fN128 = (size_t)N * 128;
  const size_t fagg  = (size_t)N * 1152;
  const size_t fRb   = (size_t)E * 192;            // E*384 bf16 in float units
  const size_t fbig  = (fRb > fagg) ? fRb : fagg;  // Rb overlaid by svt later
  const size_t ints  = (size_t)3 * N + 1 + E;
  const size_t need_new = (fN128 + fagg + fbig + ints + 64) * 4;

  float* hws  = (float*)d_ws;                    // N*128
  float* agg  = hws + fN128;                     // N*1152
  float* base2 = agg + fagg;
  float* Bws  = agg;                             // overlays agg (dead then)
  float* h0ws = agg + (size_t)N * 512;
  float* h1ws = agg + (size_t)N * 640;
  float* out0 = (float*)d_out;
  float* out1 = out0 + (size_t)N * 128;
  float* out2 = out1 + (size_t)N * 3;
  const float inv_avg = 1.f / 16.f;

  if (ws_size >= need_new) {
    // ---- new path: MFMA MLP + gather ----
    unsigned short* Rb = (unsigned short*)base2;   // E*384 bf16
    float* svt   = base2;                          // overlays Rb after k_msg
    int* counts  = (int*)(base2 + fbig);           // N
    int* cnt2    = counts + N;                     // N
    int* offs    = cnt2 + N;                       // N+1
    int* perm    = offs + N + 1;                   // E

    hipMemsetAsync(counts, 0, (size_t)2 * N * sizeof(int), stream);
    k_hist<<<(E + 511) / 512, 512, 0, stream>>>(eidx, counts, E);
    k_scan<<<1, 1024, 0, stream>>>(counts, offs, N);
    k_scatter<<<(E + 511) / 512, 512, 0, stream>>>(eidx, offs, cnt2, perm, E);

    k_gemm128<<<512, 512, 0, stream>>>(node_feats, W_up, hws, N, 1, 128, 0, 128, 0, 1.f);
    k_mlp<<<640, 512, 0, stream>>>(edge_feats, lengths, perm, Wr1, br1, Wr2, Rb, E);
    k_msg<<<2500, 256, 0, stream>>>(vectors, eidx, perm, offs, Rb, hws, agg, N, E);

    k_gemm128<<<512, 512, 0, stream>>>(agg,       Wl0, svt,       N,     1, 1152, 0,   1152, 0,   inv_avg);
    k_gemm128<<<512, 512, 0, stream>>>(agg + 128, Wl1, svt + 128, 3 * N, 3, 1152, 128, 1152, 128, inv_avg);
    k_gemm128<<<512, 512, 0, stream>>>(agg + 512, Wl2, svt + 512, 5 * N, 5, 1152, 128, 1152, 128, inv_avg);
    k_contract<<<(N * 128 + 255) / 256, 256, 0, stream>>>(svt, w0, w1, Bws, N);
    k_gemm128<<<512, 512, 0, stream>>>(Bws,       P0, h0ws, N,     1, 512, 0,   128, 0,   1.f);
    k_gemm128<<<512, 512, 0, stream>>>(Bws + 128, P1, h1ws, 3 * N, 3, 512, 128, 384, 128, 1.f);
    k_readout<<<(N + 7) / 8, 512, 0, stream>>>(h0ws, h1ws, W1, b1, W2, W3, wv,
                                               out0, out1, out2, N);
  } else {
    // ---- fallback: round-4 measured path ----
    float* svt   = base2;                          // N*1152
    int* counts  = (int*)svt;
    int* cnt2    = counts + N;
    int* offs    = cnt2 + N;
    int* perm    = offs + N + 1;

    hipMemsetAsync(counts, 0, (size_t)2 * N * sizeof(int), stream);
    k_hist<<<(E + 511) / 512, 512, 0, stream>>>(eidx, counts, E);
    k_scan<<<1, 1024, 0, stream>>>(counts, offs, N);
    k_scatter<<<(E + 511) / 512, 512, 0, stream>>>(eidx, offs, cnt2, perm, E);
    k_gemm128<<<512, 512, 0, stream>>>(node_feats, W_up, hws, N, 1, 128, 0, 128, 0, 1.f);
    k_edge_sorted<<<256, 512, 0, stream>>>(vectors, lengths, edge_feats, eidx,
                                           perm, offs, hws, Wr1, br1, Wr2, agg, N);
    k_gemm128<<<512, 512, 0, stream>>>(agg,       Wl0, svt,       N,     1, 1152, 0,   1152, 0,   inv_avg);
    k_gemm128<<<512, 512, 0, stream>>>(agg + 128, Wl1, svt + 128, 3 * N, 3, 1152, 128, 1152, 128, inv_avg);
    k_gemm128<<<512, 512, 0, stream>>>(agg + 512, Wl2, svt + 512, 5 * N, 5, 1152, 128, 1152, 128, inv_avg);
    k_contract<<<(N * 128 + 255) / 256, 256, 0, stream>>>(svt, w0, w1, Bws, N);
    k_gemm128<<<512, 512, 0, stream>>>(Bws,       P0, h0ws, N,     1, 512, 0,   128, 0,   1.f);
    k_gemm128<<<512, 512, 0, stream>>>(Bws + 128, P1, h1ws, 3 * N, 3, 512, 128, 384, 128, 1.f);
    k_readout<<<(N + 7) / 8, 512, 0, stream>>>(h0ws, h1ws, W1, b1, W2, W3, wv,
                                               out0, out1, out2, N);
  }
}